// Round 1
// baseline (1746.192 us; speedup 1.0000x reference)
//
#include <hip/hip_runtime.h>
#include <hip/hip_bf16.h>
#include <math.h>
#include <stdint.h>

#define D_  1024
#define T_  1024
#define B_  2
#define H_  8
#define HD_ 128
#define L_  4
#define V_  32000
#define M_  2048   // B_*T_

typedef __attribute__((ext_vector_type(4))) float f32x4;
typedef __attribute__((ext_vector_type(4))) short s16x4;
typedef __attribute__((ext_vector_type(8))) short s16x8;

__device__ __forceinline__ short f2bf(float f) {
  union { float f; uint32_t u; } c; c.f = f;
  uint32_t r = c.u + 0x7fffu + ((c.u >> 16) & 1u);   // RTN-even
  return (short)(r >> 16);
}

__device__ __forceinline__ s16x8 cvt8(f32x4 a, f32x4 b) {
  s16x8 r;
  r[0] = f2bf(a[0]); r[1] = f2bf(a[1]); r[2] = f2bf(a[2]); r[3] = f2bf(a[3]);
  r[4] = f2bf(b[0]); r[5] = f2bf(b[1]); r[6] = f2bf(b[2]); r[7] = f2bf(b[3]);
  return r;
}

__device__ __forceinline__ float gelu_f(float x) {
  return 0.5f * x * (1.0f + erff(x * 0.70710678118654752f));
}

// ---------------------------------------------------------------------------
// Generic bf16-MFMA GEMM: C = act(scale * A@B + bias) [+ res]
// A: [M][K] f32 (row stride lda). B: [K][N] f32 (BT=0) or [N][K] f32 (BT=1).
// Tile 128x128, BK=32, 4 waves (2x2), each wave 64x64 via 4x4 16x16x32 MFMAs.
// MODE: 0 normal; 1 causal skip (by>bx -> whole block skipped);
//       2 causal K-limit (ktiles <= (bx+1)*4).
// Batch (grid.z): offsets (z>>3)*sXb + (z&7)*sXh for X in {A,B,C}.
// ---------------------------------------------------------------------------
template<int ACT, int BIAS, int RES, int BT, int MODE>
__global__ __launch_bounds__(256)
void gemm_bf16(const float* __restrict__ A, const float* __restrict__ Bm,
               const float* __restrict__ bias, const float* __restrict__ res,
               float* __restrict__ C,
               int K, int lda, int ldb, int ldc, float scale,
               long sAb, long sAh, long sBb, long sBh, long sCb, long sCh)
{
  const int bx = blockIdx.x, by = blockIdx.y, z = blockIdx.z;
  if (MODE == 1 && by > bx) return;
  const int m0 = bx * 128, n0 = by * 128;
  int ktiles = K >> 5;
  if (MODE == 2) { int lim = (bx + 1) * 4; if (lim < ktiles) ktiles = lim; }

  const float* Ab = A  + (size_t)(z >> 3) * sAb + (size_t)(z & 7) * sAh;
  const float* Bb = Bm + (size_t)(z >> 3) * sBb + (size_t)(z & 7) * sBh;
  float*       Cb = C  + (size_t)(z >> 3) * sCb + (size_t)(z & 7) * sCh;

  // padded LDS tiles (stride 40 bf16 = 80B -> staggered banks, 16B aligned)
  __shared__ short As[2][128 * 40];
  __shared__ short Bs[2][128 * 40];

  const int tid = threadIdx.x;
  const int lane = tid & 63, wave = tid >> 6;
  const int wm = wave >> 1, wn = wave & 1;
  const int l15 = lane & 15, l4 = lane >> 4;

  const f32x4 zero4 = {0.f, 0.f, 0.f, 0.f};
  f32x4 acc[4][4];
#pragma unroll
  for (int i = 0; i < 4; ++i)
#pragma unroll
    for (int j = 0; j < 4; ++j) acc[i][j] = zero4;

  auto stageA = [&](int kt, int buf) {
    const int r = tid >> 1, c0 = (tid & 1) << 4;
    const float* src = Ab + (size_t)(m0 + r) * lda + (kt << 5) + c0;
    f32x4 v0 = *(const f32x4*)(src);
    f32x4 v1 = *(const f32x4*)(src + 4);
    f32x4 v2 = *(const f32x4*)(src + 8);
    f32x4 v3 = *(const f32x4*)(src + 12);
    short* d = &As[buf][r * 40 + c0];
    *(s16x8*)(d)     = cvt8(v0, v1);
    *(s16x8*)(d + 8) = cvt8(v2, v3);
  };

  auto stageB = [&](int kt, int buf) {
    if (BT) {
      // B is [N][K] row-major: straight copy into Bs[n][k]
      const int r = tid >> 1, c0 = (tid & 1) << 4;
      const float* src = Bb + (size_t)(n0 + r) * ldb + (kt << 5) + c0;
      f32x4 v0 = *(const f32x4*)(src);
      f32x4 v1 = *(const f32x4*)(src + 4);
      f32x4 v2 = *(const f32x4*)(src + 8);
      f32x4 v3 = *(const f32x4*)(src + 12);
      short* d = &Bs[buf][r * 40 + c0];
      *(s16x8*)(d)     = cvt8(v0, v1);
      *(s16x8*)(d + 8) = cvt8(v2, v3);
    } else {
      // B is [K][N]: transpose into Bs[n][k]; coalesced dword loads along n
      const int n = tid & 127;
      const int kqb = (tid >> 7) << 2;  // 0 or 4
#pragma unroll
      for (int p = 0; p < 4; ++p) {
        const int kq = kqb + (p << 3);
        const float* src = Bb + (size_t)((kt << 5) + kq) * ldb + n0 + n;
        s16x4 w;
        w[0] = f2bf(src[0]);
        w[1] = f2bf(src[(size_t)ldb]);
        w[2] = f2bf(src[2 * (size_t)ldb]);
        w[3] = f2bf(src[3 * (size_t)ldb]);
        *(s16x4*)&Bs[buf][n * 40 + kq] = w;
      }
    }
  };

  stageA(0, 0); stageB(0, 0);
  __syncthreads();

  for (int kt = 0; kt < ktiles; ++kt) {
    const int buf = kt & 1;
    if (kt + 1 < ktiles) { stageA(kt + 1, buf ^ 1); stageB(kt + 1, buf ^ 1); }

    const short* ap = &As[buf][(wm * 64 + l15) * 40 + l4 * 8];
    const short* bp = &Bs[buf][(wn * 64 + l15) * 40 + l4 * 8];
    s16x8 af[4], bf[4];
#pragma unroll
    for (int i = 0; i < 4; ++i) af[i] = *(const s16x8*)(ap + i * (16 * 40));
#pragma unroll
    for (int i = 0; i < 4; ++i) bf[i] = *(const s16x8*)(bp + i * (16 * 40));
#pragma unroll
    for (int i = 0; i < 4; ++i)
#pragma unroll
      for (int j = 0; j < 4; ++j)
        acc[i][j] = __builtin_amdgcn_mfma_f32_16x16x32_bf16(af[i], bf[j], acc[i][j], 0, 0, 0);
    __syncthreads();
  }

  // epilogue: D lane map col = lane&15, row = (lane>>4)*4 + r  [m89-verified]
#pragma unroll
  for (int i = 0; i < 4; ++i) {
    const int row0 = m0 + wm * 64 + i * 16 + l4 * 4;
#pragma unroll
    for (int j = 0; j < 4; ++j) {
      const int col = n0 + wn * 64 + j * 16 + l15;
      const float bv = BIAS ? bias[col] : 0.0f;
#pragma unroll
      for (int r = 0; r < 4; ++r) {
        float v = acc[i][j][r] * scale + bv;
        if (ACT == 1) v = gelu_f(v);
        if (RES) v += res[(size_t)(row0 + r) * ldc + col];
        Cb[(size_t)(row0 + r) * ldc + col] = v;
      }
    }
  }
}

// ---------------------------------------------------------------------------
// LayerNorm: one block per row of 1024
// ---------------------------------------------------------------------------
__global__ __launch_bounds__(256)
void ln_kernel(const float* __restrict__ x, const float* __restrict__ g,
               const float* __restrict__ b, float* __restrict__ y)
{
  __shared__ float red[8];
  const int row = blockIdx.x, tid = threadIdx.x;
  const float* xr = x + (size_t)row * D_;
  f32x4 v = *(const f32x4*)&xr[tid * 4];
  float s = v[0] + v[1] + v[2] + v[3];
  float s2 = v[0]*v[0] + v[1]*v[1] + v[2]*v[2] + v[3]*v[3];
#pragma unroll
  for (int off = 32; off > 0; off >>= 1) {
    s  += __shfl_xor(s, off);
    s2 += __shfl_xor(s2, off);
  }
  if ((tid & 63) == 0) { red[tid >> 6] = s; red[4 + (tid >> 6)] = s2; }
  __syncthreads();
  s  = red[0] + red[1] + red[2] + red[3];
  s2 = red[4] + red[5] + red[6] + red[7];
  const float mean = s * (1.0f / D_);
  const float var  = s2 * (1.0f / D_) - mean * mean;
  const float rs   = rsqrtf(var + 1e-5f);
  f32x4 gg = *(const f32x4*)&g[tid * 4];
  f32x4 bb = *(const f32x4*)&b[tid * 4];
  f32x4 o;
#pragma unroll
  for (int j = 0; j < 4; ++j) o[j] = (v[j] - mean) * rs * gg[j] + bb[j];
  *(f32x4*)&y[(size_t)row * D_ + tid * 4] = o;
}

// ---------------------------------------------------------------------------
// Causal softmax in place on S[16][1024][1024]; writes zeros above diagonal
// ---------------------------------------------------------------------------
__global__ __launch_bounds__(256)
void softmax_kernel(float* __restrict__ S)
{
  __shared__ float red[8];
  const int r = blockIdx.x, tid = threadIdx.x;
  const int q = r & (T_ - 1);
  float* row = S + (size_t)r * T_;
  f32x4 v = *(const f32x4*)&row[tid * 4];
  float s[4];
  float mx = -1e30f;
#pragma unroll
  for (int j = 0; j < 4; ++j) {
    const int c = tid * 4 + j;
    s[j] = (c <= q) ? v[j] : -1e30f;
    mx = fmaxf(mx, s[j]);
  }
#pragma unroll
  for (int off = 32; off > 0; off >>= 1) mx = fmaxf(mx, __shfl_xor(mx, off));
  if ((tid & 63) == 0) red[tid >> 6] = mx;
  __syncthreads();
  mx = fmaxf(fmaxf(red[0], red[1]), fmaxf(red[2], red[3]));
  float p[4];
  float sum = 0.f;
#pragma unroll
  for (int j = 0; j < 4; ++j) {
    p[j] = (tid * 4 + j <= q) ? expf(s[j] - mx) : 0.f;
    sum += p[j];
  }
#pragma unroll
  for (int off = 32; off > 0; off >>= 1) sum += __shfl_xor(sum, off);
  if ((tid & 63) == 0) red[4 + (tid >> 6)] = sum;
  __syncthreads();
  sum = red[4] + red[5] + red[6] + red[7];
  const float inv = 1.0f / sum;
  f32x4 o = {p[0] * inv, p[1] * inv, p[2] * inv, p[3] * inv};
  *(f32x4*)&row[tid * 4] = o;
}

// ---------------------------------------------------------------------------
// Embedding: h[row] = tok_emb[x[row]] + pos_emb[row % T]
// ---------------------------------------------------------------------------
__global__ __launch_bounds__(256)
void embed_kernel(const int* __restrict__ x, const float* __restrict__ tok,
                  const float* __restrict__ pos, float* __restrict__ h)
{
  const int row = blockIdx.x, tid = threadIdx.x;
  const int t = row & (T_ - 1);
  const int id = x[row];
  f32x4 a = *(const f32x4*)&tok[(size_t)id * D_ + tid * 4];
  f32x4 p = *(const f32x4*)&pos[(size_t)t * D_ + tid * 4];
  f32x4 o = {a[0] + p[0], a[1] + p[1], a[2] + p[2], a[3] + p[3]};
  *(f32x4*)&h[(size_t)row * D_ + tid * 4] = o;
}

// ---------------------------------------------------------------------------
extern "C" void kernel_launch(void* const* d_in, const int* in_sizes, int n_in,
                              void* d_out, int out_size, void* d_ws, size_t ws_size,
                              hipStream_t stream)
{
  (void)in_sizes; (void)n_in; (void)out_size; (void)ws_size;
  const int*   x     = (const int*)  d_in[0];
  const float* tok   = (const float*)d_in[1];
  const float* pos   = (const float*)d_in[2];
  const float* ln1_g = (const float*)d_in[3];
  const float* ln1_b = (const float*)d_in[4];
  const float* wqkv  = (const float*)d_in[5];
  const float* bqkv  = (const float*)d_in[6];
  const float* wo    = (const float*)d_in[7];
  const float* bo    = (const float*)d_in[8];
  const float* ln2_g = (const float*)d_in[9];
  const float* ln2_b = (const float*)d_in[10];
  const float* wfc   = (const float*)d_in[11];
  const float* wfc2  = (const float*)d_in[12];
  const float* fn_g  = (const float*)d_in[13];
  const float* fn_b  = (const float*)d_in[14];
  const float* wout  = (const float*)d_in[15];
  const float* bout  = (const float*)d_in[16];
  float* out = (float*)d_out;

  // workspace: h(8.4MB) xn(8.4MB) qkv(25.2MB) S/fc1(67.1MB) = 109MB
  float* h   = (float*)d_ws;
  float* xn  = h   + (size_t)M_ * D_;
  float* qkv = xn  + (size_t)M_ * D_;
  float* S   = qkv + (size_t)M_ * 3 * D_;   // aliases fc1 buffer

  const long sQb = (long)T_ * 3 * D_;   // per-batch stride inside qkv
  const long sSb = (long)8 * T_ * T_;   // per-batch stride of S (z = b*8+h)
  const long sSh = (long)T_ * T_;

  embed_kernel<<<M_, 256, 0, stream>>>(x, tok, pos, h);

  const float iscale = 0.08838834764831845f;   // 1/sqrt(128)

  for (int l = 0; l < L_; ++l) {
    // ln1
    ln_kernel<<<M_, 256, 0, stream>>>(h, ln1_g + l * D_, ln1_b + l * D_, xn);
    // qkv = xn @ wqkv + bqkv            [2048,1024]x[1024,3072]
    gemm_bf16<0,1,0,0,0><<<dim3(16, 24, 1), 256, 0, stream>>>(
        xn, wqkv + (size_t)l * D_ * 3 * D_, bqkv + l * 3 * D_, nullptr, qkv,
        D_, D_, 3 * D_, 3 * D_, 1.0f, 0, 0, 0, 0, 0, 0);
    // S = Q @ K^T * iscale (causal blocks only)   per (b,h): [1024,128]x[128,1024]
    gemm_bf16<0,0,0,1,1><<<dim3(8, 8, 16), 256, 0, stream>>>(
        qkv, qkv + D_, nullptr, nullptr, S,
        HD_, 3 * D_, 3 * D_, T_, iscale,
        sQb, (long)HD_, sQb, (long)HD_, sSb, sSh);
    // causal softmax rows
    softmax_kernel<<<16 * T_, 256, 0, stream>>>(S);
    // attn = P @ V   per (b,h): [1024,1024]x[1024,128], K limited per block row
    gemm_bf16<0,0,0,0,2><<<dim3(8, 1, 16), 256, 0, stream>>>(
        S, qkv + 2 * D_, nullptr, nullptr, xn,
        T_, T_, 3 * D_, D_, 1.0f,
        sSb, sSh, sQb, (long)HD_, (long)T_ * D_, (long)HD_);
    // h = h + attn @ wo + bo
    gemm_bf16<0,1,1,0,0><<<dim3(16, 8, 1), 256, 0, stream>>>(
        xn, wo + (size_t)l * D_ * D_, bo + l * D_, h, h,
        D_, D_, D_, D_, 1.0f, 0, 0, 0, 0, 0, 0);
    // ln2
    ln_kernel<<<M_, 256, 0, stream>>>(h, ln2_g + l * D_, ln2_b + l * D_, xn);
    // fc1 = gelu(xn @ wfc)              [2048,1024]x[1024,4096]
    gemm_bf16<1,0,0,0,0><<<dim3(16, 32, 1), 256, 0, stream>>>(
        xn, wfc + (size_t)l * D_ * 4 * D_, nullptr, nullptr, S,
        D_, D_, 4 * D_, 4 * D_, 1.0f, 0, 0, 0, 0, 0, 0);
    // h = h + fc1 @ wfc2                [2048,4096]x[4096,1024]
    gemm_bf16<0,0,1,0,0><<<dim3(16, 8, 1), 256, 0, stream>>>(
        S, wfc2 + (size_t)l * 4 * D_ * D_, nullptr, h, h,
        4 * D_, 4 * D_, D_, D_, 1.0f, 0, 0, 0, 0, 0, 0);
  }

  // final LN + logits
  ln_kernel<<<M_, 256, 0, stream>>>(h, fn_g, fn_b, xn);
  gemm_bf16<0,1,0,0,0><<<dim3(16, 250, 1), 256, 0, stream>>>(
      xn, wout, bout, nullptr, out,
      D_, D_, V_, V_, 1.0f, 0, 0, 0, 0, 0, 0);
}

// Round 2
// 1047.308 us; speedup vs baseline: 1.6673x; 1.6673x over previous
//
#include <hip/hip_runtime.h>
#include <math.h>
#include <stdint.h>

#define D_  1024
#define T_  1024
#define H_  8
#define HD_ 128
#define L_  4
#define V_  32000
#define M_  2048   // B*T

typedef __attribute__((ext_vector_type(4))) float f32x4;
typedef __attribute__((ext_vector_type(4))) short s16x4;
typedef __attribute__((ext_vector_type(8))) short s16x8;
typedef unsigned short u16;

__device__ __forceinline__ u16 f2bf(float f) {
  union { float f; uint32_t u; } c; c.f = f;
  uint32_t r = c.u + 0x7fffu + ((c.u >> 16) & 1u);   // RTN-even
  return (u16)(r >> 16);
}
__device__ __forceinline__ float bf2f(u16 h) {
  union { uint32_t u; float f; } c; c.u = ((uint32_t)h) << 16;
  return c.f;
}
__device__ __forceinline__ float gelu_f(float x) {
  return 0.5f * x * (1.0f + erff(x * 0.70710678118654752f));
}

// async global->LDS, 16B per lane. LDS dest must be wave-uniform base
// (HW adds lane*16); global ptr is per-lane. [guide §5, m97/m104]
__device__ __forceinline__ void gload16(const u16* g, u16* l) {
  __builtin_amdgcn_global_load_lds(
      (const __attribute__((address_space(1))) void*)(uintptr_t)g,
      (__attribute__((address_space(3))) void*)(uint32_t)(uintptr_t)l,
      16, 0, 0);
}

// ---------------------------------------------------------------------------
// Transpose-convert: in [R][C] (f32 if INF32 else bf16) -> out bf16 [C][R].
// 64x64 tiles via LDS. Grid: (C/64, R/64, Z).
// ---------------------------------------------------------------------------
template<int INF32>
__global__ __launch_bounds__(256)
void convT_kernel(const void* __restrict__ inv, u16* __restrict__ out,
                  int ldin, int ldout, long inZ, long outZ)
{
  __shared__ __align__(16) u16 tile[64][72];
  const int c0 = blockIdx.x << 6, r0 = blockIdx.y << 6;
  const int t = threadIdx.x;
  const int rr = t >> 2, cs = (t & 3) << 4;
  u16 tmp[16];
  if (INF32) {
    const float* in = (const float*)inv + (size_t)blockIdx.z * inZ;
    const float* p = in + (size_t)(r0 + rr) * ldin + c0 + cs;
#pragma unroll
    for (int q = 0; q < 4; ++q) {
      f32x4 v = *(const f32x4*)(p + q * 4);
#pragma unroll
      for (int j = 0; j < 4; ++j) tmp[q * 4 + j] = f2bf(v[j]);
    }
  } else {
    const u16* in = (const u16*)inv + (size_t)blockIdx.z * inZ;
    const u16* p = in + (size_t)(r0 + rr) * ldin + c0 + cs;
    s16x8 v0 = *(const s16x8*)(p);
    s16x8 v1 = *(const s16x8*)(p + 8);
#pragma unroll
    for (int j = 0; j < 8; ++j) { tmp[j] = (u16)v0[j]; tmp[8 + j] = (u16)v1[j]; }
  }
  *(s16x8*)&tile[rr][cs]     = *(const s16x8*)tmp;
  *(s16x8*)&tile[rr][cs + 8] = *(const s16x8*)(tmp + 8);
  __syncthreads();
  const int cr = t >> 2, rs = (t & 3) << 4;
  u16 o[16];
#pragma unroll
  for (int j = 0; j < 16; ++j) o[j] = tile[rs + j][cr];
  u16* op = out + (size_t)blockIdx.z * outZ + (size_t)(c0 + cr) * ldout + r0 + rs;
  *(s16x8*)op       = *(const s16x8*)o;
  *(s16x8*)(op + 8) = *(const s16x8*)(o + 8);
}

// ---------------------------------------------------------------------------
// bf16 MFMA GEMM (m97 2-phase structure): C = act(scale*A@B^T + bias)[+res]
// A bf16 [M][K] (lda), Bw bf16 [N][K] (ldb). BK=32, BN=128, TM in {64,128}.
// global_load_lds staging, double-buffered linear LDS [rows][32].
// OUT: 0 = bf16, 1 = f32, 2 = f32 + res (in-place h update).
// MODE: 0 none; 1 causal block skip (by>bx); 2 causal K-limit.
// Batch via blockIdx.z: offset (z>>3)*sXb + (z&7)*sXh.
// ---------------------------------------------------------------------------
template<int TM, int ACT, int BIAS, int OUT, int MODE>
__global__ __launch_bounds__(256)
void gemm2(const u16* __restrict__ A, const u16* __restrict__ Bw,
           const float* __restrict__ bias, const float* __restrict__ res,
           void* __restrict__ Cv,
           int K, int lda, int ldb, int ldc, float scale,
           long sAb, long sAh, long sBb, long sBh, long sCb, long sCh)
{
  static_assert(TM == 64 || TM == 128, "tile");
  constexpr int WN  = (TM == 128) ? 2 : 4;   // waves along N
  constexpr int WNW = 128 / WN;              // wave N-width (64 or 32)
  constexpr int NJ  = WNW / 16;              // frag cols per wave
  constexpr int AR  = TM / 64;               // A staging rounds

  const int bx = blockIdx.x, by = blockIdx.y, z = blockIdx.z;
  if (MODE == 1 && by > bx) return;
  const int m0 = bx * TM, n0 = by * 128;
  int ktiles = K >> 5;
  if (MODE == 2) { const int lim = (m0 + TM) >> 5; if (lim < ktiles) ktiles = lim; }

  const u16* Ab = A  + (size_t)(z >> 3) * sAb + (size_t)(z & 7) * sAh;
  const u16* Bb = Bw + (size_t)(z >> 3) * sBb + (size_t)(z & 7) * sBh;

  __shared__ __align__(16) u16 As[2][TM * 32];
  __shared__ __align__(16) u16 Bs[2][128 * 32];

  const int tid = threadIdx.x, lane = tid & 63, wave = tid >> 6;
  const int wm = wave / WN, wn = wave % WN;
  const int l15 = lane & 15, l4 = lane >> 4;
  const int srow = lane >> 2, scol = (lane & 3) << 3;   // staging lane map

  f32x4 acc[4][NJ];
  const f32x4 z4 = {0.f, 0.f, 0.f, 0.f};
#pragma unroll
  for (int i = 0; i < 4; ++i)
#pragma unroll
    for (int j = 0; j < NJ; ++j) acc[i][j] = z4;

  auto stage = [&](int kt, int buf) {
    const int kc = (kt << 5) + scol;
#pragma unroll
    for (int r = 0; r < AR; ++r) {
      const int row = r * 64 + wave * 16;   // wave-uniform LDS base row
      gload16(Ab + (size_t)(m0 + row + srow) * lda + kc, &As[buf][row * 32]);
    }
#pragma unroll
    for (int r = 0; r < 2; ++r) {
      const int row = r * 64 + wave * 16;
      gload16(Bb + (size_t)(n0 + row + srow) * ldb + kc, &Bs[buf][row * 32]);
    }
  };

  stage(0, 0);
  __syncthreads();

  for (int kt = 0; kt < ktiles; ++kt) {
    const int buf = kt & 1;
    if (kt + 1 < ktiles) stage(kt + 1, buf ^ 1);
    const u16* ap = &As[buf][(wm * 64 + l15) * 32 + (l4 << 3)];
    const u16* bp = &Bs[buf][(wn * WNW + l15) * 32 + (l4 << 3)];
    s16x8 af[4], bf[NJ];
#pragma unroll
    for (int i = 0; i < 4; ++i) af[i] = *(const s16x8*)(ap + i * (16 * 32));
#pragma unroll
    for (int j = 0; j < NJ; ++j) bf[j] = *(const s16x8*)(bp + j * (16 * 32));
#pragma unroll
    for (int i = 0; i < 4; ++i)
#pragma unroll
      for (int j = 0; j < NJ; ++j)
        acc[i][j] = __builtin_amdgcn_mfma_f32_16x16x32_bf16(af[i], bf[j], acc[i][j], 0, 0, 0);
    __syncthreads();
  }

  // C/D lane map: col = lane&15, row = (lane>>4)*4 + r  [m89-verified]
  const size_t cbase = (size_t)(z >> 3) * sCb + (size_t)(z & 7) * sCh;
  float* Cf = (float*)Cv;
  u16*   Ch = (u16*)Cv;
#pragma unroll
  for (int i = 0; i < 4; ++i) {
    const int row0 = m0 + wm * 64 + i * 16 + l4 * 4;
#pragma unroll
    for (int j = 0; j < NJ; ++j) {
      const int col = n0 + wn * WNW + j * 16 + l15;
      const float bv = BIAS ? bias[col] : 0.0f;
#pragma unroll
      for (int r = 0; r < 4; ++r) {
        float v = acc[i][j][r] * scale + bv;
        if (ACT) v = gelu_f(v);
        const size_t idx = cbase + (size_t)(row0 + r) * ldc + col;
        if (OUT == 0)      Ch[idx] = f2bf(v);
        else if (OUT == 1) Cf[idx] = v;
        else               Cf[idx] = v + res[idx];
      }
    }
  }
}

// ---------------------------------------------------------------------------
// LayerNorm: f32 in -> bf16 out. One block per row of 1024.
// ---------------------------------------------------------------------------
__global__ __launch_bounds__(256)
void ln_bf16(const float* __restrict__ x, const float* __restrict__ g,
             const float* __restrict__ b, u16* __restrict__ y)
{
  __shared__ float red[8];
  const int row = blockIdx.x, tid = threadIdx.x;
  f32x4 v = *(const f32x4*)&x[(size_t)row * D_ + tid * 4];
  float s  = v[0] + v[1] + v[2] + v[3];
  float s2 = v[0]*v[0] + v[1]*v[1] + v[2]*v[2] + v[3]*v[3];
#pragma unroll
  for (int off = 32; off > 0; off >>= 1) {
    s  += __shfl_xor(s, off);
    s2 += __shfl_xor(s2, off);
  }
  if ((tid & 63) == 0) { red[tid >> 6] = s; red[4 + (tid >> 6)] = s2; }
  __syncthreads();
  s  = red[0] + red[1] + red[2] + red[3];
  s2 = red[4] + red[5] + red[6] + red[7];
  const float mean = s * (1.0f / D_);
  const float var  = s2 * (1.0f / D_) - mean * mean;
  const float rs   = rsqrtf(var + 1e-5f);
  f32x4 gg = *(const f32x4*)&g[tid * 4];
  f32x4 bb = *(const f32x4*)&b[tid * 4];
  u16 o[4];
#pragma unroll
  for (int j = 0; j < 4; ++j) o[j] = f2bf((v[j] - mean) * rs * gg[j] + bb[j]);
  *(s16x4*)&y[(size_t)row * D_ + tid * 4] = *(const s16x4*)o;
}

// ---------------------------------------------------------------------------
// Causal softmax in place on bf16 S[16][1024][1024]; zeros above diagonal.
// ---------------------------------------------------------------------------
__global__ __launch_bounds__(256)
void softmax_bf16(u16* __restrict__ S)
{
  __shared__ float red[8];
  const int rI = blockIdx.x, tid = threadIdx.x;
  const int q = rI & (T_ - 1);
  u16* row = S + (size_t)rI * T_;
  s16x4 v = *(const s16x4*)&row[tid * 4];
  float s[4];
  float mx = -1e30f;
#pragma unroll
  for (int j = 0; j < 4; ++j) {
    const int c = tid * 4 + j;
    s[j] = (c <= q) ? bf2f((u16)v[j]) : -1e30f;
    mx = fmaxf(mx, s[j]);
  }
#pragma unroll
  for (int off = 32; off > 0; off >>= 1) mx = fmaxf(mx, __shfl_xor(mx, off));
  if ((tid & 63) == 0) red[tid >> 6] = mx;
  __syncthreads();
  mx = fmaxf(fmaxf(red[0], red[1]), fmaxf(red[2], red[3]));
  float p[4], sum = 0.f;
#pragma unroll
  for (int j = 0; j < 4; ++j) {
    p[j] = (tid * 4 + j <= q) ? __expf(s[j] - mx) : 0.f;
    sum += p[j];
  }
#pragma unroll
  for (int off = 32; off > 0; off >>= 1) sum += __shfl_xor(sum, off);
  if ((tid & 63) == 0) red[4 + (tid >> 6)] = sum;
  __syncthreads();
  sum = red[4] + red[5] + red[6] + red[7];
  const float inv = 1.0f / sum;
  u16 o[4];
#pragma unroll
  for (int j = 0; j < 4; ++j) o[j] = f2bf(p[j] * inv);
  *(s16x4*)&row[tid * 4] = *(const s16x4*)o;
}

// ---------------------------------------------------------------------------
// Embedding: h[row] = tok_emb[x[row]] + pos_emb[row % T]   (f32 out)
// ---------------------------------------------------------------------------
__global__ __launch_bounds__(256)
void embed_kernel(const int* __restrict__ x, const float* __restrict__ tok,
                  const float* __restrict__ pos, float* __restrict__ h)
{
  const int row = blockIdx.x, tid = threadIdx.x;
  const int t = row & (T_ - 1);
  const int id = x[row];
  f32x4 a = *(const f32x4*)&tok[(size_t)id * D_ + tid * 4];
  f32x4 p = *(const f32x4*)&pos[(size_t)t * D_ + tid * 4];
  f32x4 o = {a[0] + p[0], a[1] + p[1], a[2] + p[2], a[3] + p[3]};
  *(f32x4*)&h[(size_t)row * D_ + tid * 4] = o;
}

// ---------------------------------------------------------------------------
extern "C" void kernel_launch(void* const* d_in, const int* in_sizes, int n_in,
                              void* d_out, int out_size, void* d_ws, size_t ws_size,
                              hipStream_t stream)
{
  (void)in_sizes; (void)n_in; (void)out_size; (void)ws_size;
  const int*   x     = (const int*)  d_in[0];
  const float* tok   = (const float*)d_in[1];
  const float* pos   = (const float*)d_in[2];
  const float* ln1_g = (const float*)d_in[3];
  const float* ln1_b = (const float*)d_in[4];
  const float* wqkv  = (const float*)d_in[5];
  const float* bqkv  = (const float*)d_in[6];
  const float* wo    = (const float*)d_in[7];
  const float* bo    = (const float*)d_in[8];
  const float* ln2_g = (const float*)d_in[9];
  const float* ln2_b = (const float*)d_in[10];
  const float* wfc   = (const float*)d_in[11];
  const float* wfc2  = (const float*)d_in[12];
  const float* fn_g  = (const float*)d_in[13];
  const float* fn_b  = (const float*)d_in[14];
  const float* wout  = (const float*)d_in[15];
  const float* bout  = (const float*)d_in[16];
  float* out = (float*)d_out;

  // ws layout (88.1 MB total):
  // h f32 | xn bf16 | Wslot bf16 (qkvT,woT,fcT,fc2T = 25.2MB) | qkv | Vt | S/fc1
  // woutT (65.5MB) overlays Wslot..S after the layers (all dead by then).
  float* h  = (float*)d_ws;                 // 2048*1024 f32
  u16* xn   = (u16*)(h + (size_t)M_ * D_);  // 2048*1024
  u16* Wq   = xn  + (size_t)M_ * D_;        // 3072*1024
  u16* Wo   = Wq  + (size_t)3 * D_ * D_;    // 1024*1024
  u16* Wf1  = Wo  + (size_t)D_ * D_;        // 4096*1024
  u16* Wf2  = Wf1 + (size_t)4 * D_ * D_;    // 1024*4096
  u16* qkv  = Wf2 + (size_t)4 * D_ * D_;    // 2048*3072
  u16* Vt   = qkv + (size_t)M_ * 3 * D_;    // 2*1024*1024  [bh][hd][t]
  u16* S    = Vt  + (size_t)2 * T_ * D_;    // 16*1024*1024 (fc1 aliases)
  u16* WoutT = Wq;                          // 32000*1024 overlay

  const long sQb = (long)T_ * 3 * D_;       // qkv per-batch row stride
  const long sSb = (long)8 * T_ * T_;
  const long sSh = (long)T_ * T_;
  const float iscale = 0.08838834764831845f;  // 1/sqrt(128)

  embed_kernel<<<M_, 256, 0, stream>>>(x, tok, pos, h);

  for (int l = 0; l < L_; ++l) {
    // weight transpose-converts for this layer (into Wslot)
    convT_kernel<1><<<dim3(48, 16, 1), 256, 0, stream>>>(
        wqkv + (size_t)l * D_ * 3 * D_, Wq, 3 * D_, D_, 0, 0);
    convT_kernel<1><<<dim3(16, 16, 1), 256, 0, stream>>>(
        wo + (size_t)l * D_ * D_, Wo, D_, D_, 0, 0);
    convT_kernel<1><<<dim3(64, 16, 1), 256, 0, stream>>>(
        wfc + (size_t)l * D_ * 4 * D_, Wf1, 4 * D_, D_, 0, 0);
    convT_kernel<1><<<dim3(16, 64, 1), 256, 0, stream>>>(
        wfc2 + (size_t)l * 4 * D_ * D_, Wf2, D_, 4 * D_, 0, 0);

    // ln1 -> xn (bf16)
    ln_bf16<<<M_, 256, 0, stream>>>(h, ln1_g + l * D_, ln1_b + l * D_, xn);
    // qkv = xn @ WqT + bqkv
    gemm2<128, 0, 1, 0, 0><<<dim3(16, 24, 1), 256, 0, stream>>>(
        xn, Wq, bqkv + l * 3 * D_, nullptr, qkv,
        D_, D_, D_, 3 * D_, 1.0f, 0, 0, 0, 0, 0, 0);
    // S = Q @ K^T * iscale (lower-triangle blocks only)
    gemm2<128, 0, 0, 0, 1><<<dim3(8, 8, 16), 256, 0, stream>>>(
        qkv, qkv + D_, nullptr, nullptr, S,
        HD_, 3 * D_, 3 * D_, T_, iscale,
        sQb, (long)HD_, sQb, (long)HD_, sSb, sSh);
    softmax_bf16<<<16 * T_, 256, 0, stream>>>(S);
    // V^T per batch: qkv cols 2048.. -> Vt[bh][hd][t]
    convT_kernel<0><<<dim3(16, 16, 2), 256, 0, stream>>>(
        qkv + 2 * D_, Vt, 3 * D_, T_, (long)T_ * 3 * D_, (long)T_ * D_);
    // attn = P @ Vt^T (K limited to causal extent)
    gemm2<64, 0, 0, 0, 2><<<dim3(16, 1, 16), 256, 0, stream>>>(
        S, Vt, nullptr, nullptr, xn,
        T_, T_, T_, D_, 1.0f,
        sSb, sSh, (long)T_ * D_, (long)HD_ * T_, (long)T_ * D_, (long)HD_);
    // h += attn @ WoT + bo
    gemm2<64, 0, 1, 2, 0><<<dim3(32, 8, 1), 256, 0, stream>>>(
        xn, Wo, bo + l * D_, h, h,
        D_, D_, D_, D_, 1.0f, 0, 0, 0, 0, 0, 0);
    // ln2 -> xn
    ln_bf16<<<M_, 256, 0, stream>>>(h, ln2_g + l * D_, ln2_b + l * D_, xn);
    // fc1 = gelu(xn @ Wf1T)  (into S region)
    gemm2<128, 1, 0, 0, 0><<<dim3(16, 32, 1), 256, 0, stream>>>(
        xn, Wf1, nullptr, nullptr, S,
        D_, D_, D_, 4 * D_, 1.0f, 0, 0, 0, 0, 0, 0);
    // h += fc1 @ Wf2T
    gemm2<64, 0, 0, 2, 0><<<dim3(32, 8, 1), 256, 0, stream>>>(
        S, Wf2, nullptr, h, h,
        4 * D_, 4 * D_, 4 * D_, D_, 1.0f, 0, 0, 0, 0, 0, 0);
  }

  // final LN -> xn; wout^T into overlay; logits (f32 out)
  ln_bf16<<<M_, 256, 0, stream>>>(h, fn_g, fn_b, xn);
  convT_kernel<1><<<dim3(500, 16, 1), 256, 0, stream>>>(
      wout, WoutT, V_, D_, 0, 0);
  gemm2<128, 0, 1, 1, 0><<<dim3(16, 250, 1), 256, 0, stream>>>(
      xn, WoutT, bout, nullptr, out,
      D_, D_, D_, V_, 1.0f, 0, 0, 0, 0, 0, 0);
}

// Round 3
// 996.739 us; speedup vs baseline: 1.7519x; 1.0507x over previous
//
#include <hip/hip_runtime.h>
#include <math.h>
#include <stdint.h>

#define D_  1024
#define T_  1024
#define H_  8
#define HD_ 128
#define L_  4
#define V_  32000
#define M_  2048   // B*T

typedef __attribute__((ext_vector_type(4))) float f32x4;
typedef __attribute__((ext_vector_type(4))) short s16x4;
typedef __attribute__((ext_vector_type(8))) short s16x8;
typedef unsigned short u16;

__device__ __forceinline__ u16 f2bf(float f) {
  union { float f; uint32_t u; } c; c.f = f;
  uint32_t r = c.u + 0x7fffu + ((c.u >> 16) & 1u);   // RTN-even
  return (u16)(r >> 16);
}
__device__ __forceinline__ float bf2f(u16 h) {
  union { uint32_t u; float f; } c; c.u = ((uint32_t)h) << 16;
  return c.f;
}
__device__ __forceinline__ float gelu_f(float x) {
  return 0.5f * x * (1.0f + erff(x * 0.70710678118654752f));
}

// async global->LDS, 16B per lane. LDS dest is wave-uniform base (HW adds
// lane*16); global ptr is per-lane. [guide §5, m97/m104]
__device__ __forceinline__ void gload16(const u16* g, u16* l) {
  __builtin_amdgcn_global_load_lds(
      (const __attribute__((address_space(1))) void*)(uintptr_t)g,
      (__attribute__((address_space(3))) void*)(uint32_t)(uintptr_t)l,
      16, 0, 0);
}

// ---------------------------------------------------------------------------
// Transpose-convert: in [R][C] (f32 if INF32 else bf16) -> out bf16 [C][R].
// 64x64 tiles via LDS. Grid: (C/64, R/64, Z).
// ---------------------------------------------------------------------------
template<int INF32>
__global__ __launch_bounds__(256)
void convT_kernel(const void* __restrict__ inv, u16* __restrict__ out,
                  int ldin, int ldout, long inZ, long outZ)
{
  __shared__ __align__(16) u16 tile[64][72];
  const int c0 = blockIdx.x << 6, r0 = blockIdx.y << 6;
  const int t = threadIdx.x;
  const int rr = t >> 2, cs = (t & 3) << 4;
  u16 tmp[16];
  if (INF32) {
    const float* in = (const float*)inv + (size_t)blockIdx.z * inZ;
    const float* p = in + (size_t)(r0 + rr) * ldin + c0 + cs;
#pragma unroll
    for (int q = 0; q < 4; ++q) {
      f32x4 v = *(const f32x4*)(p + q * 4);
#pragma unroll
      for (int j = 0; j < 4; ++j) tmp[q * 4 + j] = f2bf(v[j]);
    }
  } else {
    const u16* in = (const u16*)inv + (size_t)blockIdx.z * inZ;
    const u16* p = in + (size_t)(r0 + rr) * ldin + c0 + cs;
    s16x8 v0 = *(const s16x8*)(p);
    s16x8 v1 = *(const s16x8*)(p + 8);
#pragma unroll
    for (int j = 0; j < 8; ++j) { tmp[j] = (u16)v0[j]; tmp[8 + j] = (u16)v1[j]; }
  }
  *(s16x8*)&tile[rr][cs]     = *(const s16x8*)tmp;
  *(s16x8*)&tile[rr][cs + 8] = *(const s16x8*)(tmp + 8);
  __syncthreads();
  const int cr = t >> 2, rs = (t & 3) << 4;
  u16 o[16];
#pragma unroll
  for (int j = 0; j < 16; ++j) o[j] = tile[rs + j][cr];
  u16* op = out + (size_t)blockIdx.z * outZ + (size_t)(c0 + cr) * ldout + r0 + rs;
  *(s16x8*)op       = *(const s16x8*)o;
  *(s16x8*)(op + 8) = *(const s16x8*)(o + 8);
}

// ---------------------------------------------------------------------------
// bf16 MFMA GEMM (2-phase m97 structure) + T1 XCD swizzle.
// A bf16 [M][K] (lda), Bw bf16 [N][K] (ldb). BK=32, BN=128, TM in {64,128}.
// OUT: 0 = bf16, 1 = f32, 2 = f32 + res. MODE: 0 none; 1 causal block skip;
// 2 causal K-limit. Batch via z: offset (z>>3)*sXb + (z&7)*sXh.
// NOTE: total grid blocks must be a multiple of 8 (bijective XCD swizzle).
// ---------------------------------------------------------------------------
template<int TM, int ACT, int BIAS, int OUT, int MODE>
__global__ __launch_bounds__(256)
void gemm2(const u16* __restrict__ A, const u16* __restrict__ Bw,
           const float* __restrict__ bias, const float* __restrict__ res,
           void* __restrict__ Cv,
           int K, int lda, int ldb, int ldc, float scale,
           long sAb, long sAh, long sBb, long sBh, long sCb, long sCh)
{
  static_assert(TM == 64 || TM == 128, "tile");
  constexpr int WN  = (TM == 128) ? 2 : 4;
  constexpr int WNW = 128 / WN;
  constexpr int NJ  = WNW / 16;
  constexpr int AR  = TM / 64;

  // T1: XCD-chunked block swizzle (nwg % 8 == 0 at every call site)
  const int gx = gridDim.x, gy = gridDim.y;
  int flat = (blockIdx.z * gy + blockIdx.y) * gx + blockIdx.x;
  const int nwg = gx * gy * gridDim.z;
  int swz = (flat & 7) * (nwg >> 3) + (flat >> 3);
  const int bx = swz % gx; swz /= gx;
  const int by = swz % gy;
  const int z  = swz / gy;

  if (MODE == 1 && by > bx) return;
  const int m0 = bx * TM, n0 = by * 128;
  int ktiles = K >> 5;
  if (MODE == 2) { const int lim = (m0 + TM) >> 5; if (lim < ktiles) ktiles = lim; }

  const u16* Ab = A  + (size_t)(z >> 3) * sAb + (size_t)(z & 7) * sAh;
  const u16* Bb = Bw + (size_t)(z >> 3) * sBb + (size_t)(z & 7) * sBh;

  __shared__ __align__(16) u16 As[2][TM * 32];
  __shared__ __align__(16) u16 Bs[2][128 * 32];

  const int tid = threadIdx.x, lane = tid & 63, wave = tid >> 6;
  const int wm = wave / WN, wn = wave % WN;
  const int l15 = lane & 15, l4 = lane >> 4;
  const int srow = lane >> 2, scol = (lane & 3) << 3;

  f32x4 acc[4][NJ];
  const f32x4 z4 = {0.f, 0.f, 0.f, 0.f};
#pragma unroll
  for (int i = 0; i < 4; ++i)
#pragma unroll
    for (int j = 0; j < NJ; ++j) acc[i][j] = z4;

  auto stage = [&](int kt, int buf) {
    const int kc = (kt << 5) + scol;
#pragma unroll
    for (int r = 0; r < AR; ++r) {
      const int row = r * 64 + wave * 16;
      gload16(Ab + (size_t)(m0 + row + srow) * lda + kc, &As[buf][row * 32]);
    }
#pragma unroll
    for (int r = 0; r < 2; ++r) {
      const int row = r * 64 + wave * 16;
      gload16(Bb + (size_t)(n0 + row + srow) * ldb + kc, &Bs[buf][row * 32]);
    }
  };

  stage(0, 0);
  __syncthreads();

  for (int kt = 0; kt < ktiles; ++kt) {
    const int buf = kt & 1;
    if (kt + 1 < ktiles) stage(kt + 1, buf ^ 1);
    const u16* ap = &As[buf][(wm * 64 + l15) * 32 + (l4 << 3)];
    const u16* bp = &Bs[buf][(wn * WNW + l15) * 32 + (l4 << 3)];
    s16x8 af[4], bf[NJ];
#pragma unroll
    for (int i = 0; i < 4; ++i) af[i] = *(const s16x8*)(ap + i * (16 * 32));
#pragma unroll
    for (int j = 0; j < NJ; ++j) bf[j] = *(const s16x8*)(bp + j * (16 * 32));
#pragma unroll
    for (int i = 0; i < 4; ++i)
#pragma unroll
      for (int j = 0; j < NJ; ++j)
        acc[i][j] = __builtin_amdgcn_mfma_f32_16x16x32_bf16(af[i], bf[j], acc[i][j], 0, 0, 0);
    __syncthreads();
  }

  // C/D lane map: col = lane&15, row = (lane>>4)*4 + r  [m89-verified]
  const size_t cbase = (size_t)(z >> 3) * sCb + (size_t)(z & 7) * sCh;
  float* Cf = (float*)Cv;
  u16*   Ch = (u16*)Cv;
#pragma unroll
  for (int i = 0; i < 4; ++i) {
    const int row0 = m0 + wm * 64 + i * 16 + l4 * 4;
#pragma unroll
    for (int j = 0; j < NJ; ++j) {
      const int col = n0 + wn * WNW + j * 16 + l15;
      const float bv = BIAS ? bias[col] : 0.0f;
#pragma unroll
      for (int r = 0; r < 4; ++r) {
        float v = acc[i][j][r] * scale + bv;
        if (ACT) v = gelu_f(v);
        const size_t idx = cbase + (size_t)(row0 + r) * ldc + col;
        if (OUT == 0)      Ch[idx] = f2bf(v);
        else if (OUT == 1) Cf[idx] = v;
        else               Cf[idx] = v + res[idx];
      }
    }
  }
}

// ---------------------------------------------------------------------------
// 256x256 8-phase GEMM for the logits layer (T2+T3+T4+T5, m201 template).
// A bf16 [2048][1024], Bw bf16 [32000][1024], C f32 [2048][32000], + bias.
// BK=64 K-tiles stored as K-half slots [256 rows][32 k] (16 KB each);
// per buffer: Ak0,Ak1,Bk0,Bk1; two buffers (even/odd tiles) = 128 KiB LDS.
// Phase p of a tile computes (kk, mhalf); stages exactly one half-slot;
// vmcnt(4) only at phases 4/8. XOR k-slot swizzle (both-sides involution).
// ---------------------------------------------------------------------------
__global__ __launch_bounds__(512, 2)
void gemm8_logits(const u16* __restrict__ A, const u16* __restrict__ Bw,
                  const float* __restrict__ bias, float* __restrict__ C)
{
  // T1 swizzle: 1000 blocks, cpx=125; decode bx = swz%8 (M), by = swz/8 (N)
  int flat = blockIdx.x;
  int swz = (flat & 7) * 125 + (flat >> 3);
  const int bx = swz & 7;
  const int by = swz >> 3;
  const int m0 = bx << 8, n0 = by << 8;

  __shared__ __align__(16) u16 lds[65536];   // 128 KiB
  // u16 offsets within lds: buf b at b*32768; Ak0 +0, Ak1 +8192,
  // Bk0 +16384, Bk1 +24576.

  const int tid = threadIdx.x, lane = tid & 63, wave = tid >> 6;
  const int wm = wave >> 2, wn = wave & 3;       // 2M x 4N waves
  const int l15 = lane & 15, l4 = lane >> 4;

  f32x4 acc[8][4];
  const f32x4 z4 = {0.f, 0.f, 0.f, 0.f};
#pragma unroll
  for (int i = 0; i < 8; ++i)
#pragma unroll
    for (int j = 0; j < 4; ++j) acc[i][j] = z4;

  // stage one K-half slot (256 rows x 32 k = 16 KB) = 2 gloads per wave.
  // LDS unit u = r*512 + wave*64 + lane -> (row = u>>2, ks = u&3);
  // source k-slot pre-swizzled: ks ^ ((row>>1)&3)  [rule #21 both-sides]
  auto stg = [&](const u16* G, int rowbase, int slot, int kt, int kh) {
    if (kt >= 16) return;
#pragma unroll
    for (int r = 0; r < 2; ++r) {
      const int u = r * 512 + (wave << 6) + lane;
      const int rw = u >> 2, ks = u & 3;
      const int ksw = ks ^ ((rw >> 1) & 3);
      const u16* src = G + (size_t)(rowbase + rw) * 1024 + (kt << 6) + (kh << 5) + (ksw << 3);
      gload16(src, &lds[slot + r * 4096 + (wave << 9)]);
    }
  };

  s16x8 af[4], bfr[4];

#define LDA4(bb, kk, mh)                                                      \
  {                                                                           \
    _Pragma("unroll") for (int f = 0; f < 4; ++f) {                           \
      const int rw = wm * 128 + (mh) * 64 + f * 16 + l15;                     \
      af[f] = *(const s16x8*)&lds[(bb) + (kk) * 8192 + rw * 32 +              \
                                  ((l4 ^ ((rw >> 1) & 3)) << 3)];             \
    }                                                                         \
  }
#define LDB4(bb, kk)                                                          \
  {                                                                           \
    _Pragma("unroll") for (int f = 0; f < 4; ++f) {                           \
      const int rn = wn * 64 + f * 16 + l15;                                  \
      bfr[f] = *(const s16x8*)&lds[(bb) + 16384 + (kk) * 8192 + rn * 32 +     \
                                   ((l4 ^ ((rn >> 1) & 3)) << 3)];            \
    }                                                                         \
  }
#define MFMA16(mh)                                                            \
  {                                                                           \
    __builtin_amdgcn_s_barrier();                                             \
    asm volatile("s_waitcnt lgkmcnt(0)" ::: "memory");                        \
    __builtin_amdgcn_sched_barrier(0);                                        \
    __builtin_amdgcn_s_setprio(1);                                            \
    _Pragma("unroll") for (int f = 0; f < 4; ++f)                             \
      _Pragma("unroll") for (int nf = 0; nf < 4; ++nf)                        \
        acc[(mh) * 4 + f][nf] = __builtin_amdgcn_mfma_f32_16x16x32_bf16(      \
            af[f], bfr[nf], acc[(mh) * 4 + f][nf], 0, 0, 0);                  \
    __builtin_amdgcn_s_setprio(0);                                            \
  }
#define BAR() __builtin_amdgcn_s_barrier()
#define VM4() asm volatile("s_waitcnt vmcnt(4)" ::: "memory")

  // prologue: tile0 all 4 halves + tile1 {Ak0, Bk0}; wait tile0 landed
  stg(A,  m0, 0,             0, 0);
  stg(Bw, n0, 16384,         0, 0);
  stg(A,  m0, 8192,          0, 1);
  stg(Bw, n0, 16384 + 8192,  0, 1);
  stg(A,  m0, 32768,         1, 0);
  stg(Bw, n0, 32768 + 16384, 1, 0);
  VM4();
  BAR();

  for (int i = 0; i < 8; ++i) {
    const int t = 2 * i;
    // ph1: buf0 kk0 mh0 (+B), stage (t+1).Ak1 -> buf1.Ak1
    LDA4(0, 0, 0); LDB4(0, 0);
    stg(A, m0, 32768 + 8192, t + 1, 1);
    MFMA16(0); BAR();
    // ph2: buf0 kk0 mh1, stage (t+1).Bk1 -> buf1.Bk1
    LDA4(0, 0, 1);
    stg(Bw, n0, 32768 + 24576, t + 1, 1);
    MFMA16(1); BAR();
    // ph3: buf0 kk1 mh0 (+B), stage (t+2).Ak0 -> buf0.Ak0
    LDA4(0, 1, 0); LDB4(0, 1);
    stg(A, m0, 0, t + 2, 0);
    MFMA16(0); BAR();
    // ph4: buf0 kk1 mh1, stage (t+2).Bk0 -> buf0.Bk0 ; vmcnt(4)
    LDA4(0, 1, 1);
    stg(Bw, n0, 16384, t + 2, 0);
    MFMA16(1); VM4(); BAR();
    // ph5: buf1 kk0 mh0 (+B), stage (t+2).Ak1 -> buf0.Ak1
    LDA4(32768, 0, 0); LDB4(32768, 0);
    stg(A, m0, 8192, t + 2, 1);
    MFMA16(0); BAR();
    // ph6: buf1 kk0 mh1, stage (t+2).Bk1 -> buf0.Bk1
    LDA4(32768, 0, 1);
    stg(Bw, n0, 16384 + 8192, t + 2, 1);
    MFMA16(1); BAR();
    // ph7: buf1 kk1 mh0 (+B), stage (t+3).Ak0 -> buf1.Ak0
    LDA4(32768, 1, 0); LDB4(32768, 1);
    stg(A, m0, 32768, t + 3, 0);
    MFMA16(0); BAR();
    // ph8: buf1 kk1 mh1, stage (t+3).Bk0 -> buf1.Bk0 ; vmcnt(4)
    LDA4(32768, 1, 1);
    stg(Bw, n0, 32768 + 16384, t + 3, 0);
    MFMA16(1); VM4(); BAR();
  }
#undef LDA4
#undef LDB4
#undef MFMA16
#undef BAR
#undef VM4

  // epilogue: col = l15, row = l4*4 + r per 16x16 fragment [m89]
  float bv[4];
#pragma unroll
  for (int nf = 0; nf < 4; ++nf) bv[nf] = bias[n0 + wn * 64 + nf * 16 + l15];
#pragma unroll
  for (int mf = 0; mf < 8; ++mf) {
    const int row0 = m0 + wm * 128 + mf * 16 + l4 * 4;
#pragma unroll
    for (int nf = 0; nf < 4; ++nf) {
      const int col = n0 + wn * 64 + nf * 16 + l15;
#pragma unroll
      for (int r = 0; r < 4; ++r)
        C[(size_t)(row0 + r) * V_ + col] = acc[mf][nf][r] + bv[nf];
    }
  }
}

// ---------------------------------------------------------------------------
// LayerNorm: f32 in -> bf16 out. One block per row of 1024.
// ---------------------------------------------------------------------------
__global__ __launch_bounds__(256)
void ln_bf16(const float* __restrict__ x, const float* __restrict__ g,
             const float* __restrict__ b, u16* __restrict__ y)
{
  __shared__ float red[8];
  const int row = blockIdx.x, tid = threadIdx.x;
  f32x4 v = *(const f32x4*)&x[(size_t)row * D_ + tid * 4];
  float s  = v[0] + v[1] + v[2] + v[3];
  float s2 = v[0]*v[0] + v[1]*v[1] + v[2]*v[2] + v[3]*v[3];
#pragma unroll
  for (int off = 32; off > 0; off >>= 1) {
    s  += __shfl_xor(s, off);
    s2 += __shfl_xor(s2, off);
  }
  if ((tid & 63) == 0) { red[tid >> 6] = s; red[4 + (tid >> 6)] = s2; }
  __syncthreads();
  s  = red[0] + red[1] + red[2] + red[3];
  s2 = red[4] + red[5] + red[6] + red[7];
  const float mean = s * (1.0f / D_);
  const float var  = s2 * (1.0f / D_) - mean * mean;
  const float rs   = rsqrtf(var + 1e-5f);
  f32x4 gg = *(const f32x4*)&g[tid * 4];
  f32x4 bb = *(const f32x4*)&b[tid * 4];
  u16 o[4];
#pragma unroll
  for (int j = 0; j < 4; ++j) o[j] = f2bf((v[j] - mean) * rs * gg[j] + bb[j]);
  *(s16x4*)&y[(size_t)row * D_ + tid * 4] = *(const s16x4*)o;
}

// ---------------------------------------------------------------------------
// Causal softmax in place on bf16 S[16][1024][1024]; one wave per row.
// Block = 4 rows. Lane holds 16 contiguous cols (32B) -> shuffle-only reduce.
// ---------------------------------------------------------------------------
__global__ __launch_bounds__(256)
void softmax_bf16(u16* __restrict__ S)
{
  const int rI = blockIdx.x * 4 + (threadIdx.x >> 6);
  const int lane = threadIdx.x & 63;
  const int q = rI & (T_ - 1);
  u16* row = S + (size_t)rI * T_;
  s16x8 v0 = *(const s16x8*)&row[lane * 16];
  s16x8 v1 = *(const s16x8*)&row[lane * 16 + 8];
  float s[16];
  float mx = -1e30f;
#pragma unroll
  for (int j = 0; j < 16; ++j) {
    const int c = lane * 16 + j;
    const u16 raw = (u16)(j < 8 ? v0[j] : v1[j - 8]);
    s[j] = (c <= q) ? bf2f(raw) : -1e30f;
    mx = fmaxf(mx, s[j]);
  }
#pragma unroll
  for (int off = 32; off > 0; off >>= 1) mx = fmaxf(mx, __shfl_xor(mx, off));
  float sum = 0.f;
#pragma unroll
  for (int j = 0; j < 16; ++j) {
    s[j] = (lane * 16 + j <= q) ? __expf(s[j] - mx) : 0.f;
    sum += s[j];
  }
#pragma unroll
  for (int off = 32; off > 0; off >>= 1) sum += __shfl_xor(sum, off);
  const float inv = 1.0f / sum;
  s16x8 o0, o1;
#pragma unroll
  for (int j = 0; j < 8; ++j) {
    o0[j] = (short)f2bf(s[j] * inv);
    o1[j] = (short)f2bf(s[j + 8] * inv);
  }
  *(s16x8*)&row[lane * 16]     = o0;
  *(s16x8*)&row[lane * 16 + 8] = o1;
}

// ---------------------------------------------------------------------------
// Embedding: h[row] = tok_emb[x[row]] + pos_emb[row % T]   (f32 out)
// ---------------------------------------------------------------------------
__global__ __launch_bounds__(256)
void embed_kernel(const int* __restrict__ x, const float* __restrict__ tok,
                  const float* __restrict__ pos, float* __restrict__ h)
{
  const int row = blockIdx.x, tid = threadIdx.x;
  const int t = row & (T_ - 1);
  const int id = x[row];
  f32x4 a = *(const f32x4*)&tok[(size_t)id * D_ + tid * 4];
  f32x4 p = *(const f32x4*)&pos[(size_t)t * D_ + tid * 4];
  f32x4 o = {a[0] + p[0], a[1] + p[1], a[2] + p[2], a[3] + p[3]};
  *(f32x4*)&h[(size_t)row * D_ + tid * 4] = o;
}

// ---------------------------------------------------------------------------
extern "C" void kernel_launch(void* const* d_in, const int* in_sizes, int n_in,
                              void* d_out, int out_size, void* d_ws, size_t ws_size,
                              hipStream_t stream)
{
  (void)in_sizes; (void)n_in; (void)out_size; (void)ws_size;
  const int*   x     = (const int*)  d_in[0];
  const float* tok   = (const float*)d_in[1];
  const float* pos   = (const float*)d_in[2];
  const float* ln1_g = (const float*)d_in[3];
  const float* ln1_b = (const float*)d_in[4];
  const float* wqkv  = (const float*)d_in[5];
  const float* bqkv  = (const float*)d_in[6];
  const float* wo    = (const float*)d_in[7];
  const float* bo    = (const float*)d_in[8];
  const float* ln2_g = (const float*)d_in[9];
  const float* ln2_b = (const float*)d_in[10];
  const float* wfc   = (const float*)d_in[11];
  const float* wfc2  = (const float*)d_in[12];
  const float* fn_g  = (const float*)d_in[13];
  const float* fn_b  = (const float*)d_in[14];
  const float* wout  = (const float*)d_in[15];
  const float* bout  = (const float*)d_in[16];
  float* out = (float*)d_out;

  // ws layout (88.1 MB total):
  // h f32 | xn bf16 | Wslot bf16 (qkvT,woT,fcT,fc2T = 25.2MB) | qkv | Vt | S/fc1
  // woutT (65.5MB) overlays Wslot..S after the layers (all dead by then).
  float* h  = (float*)d_ws;                 // 2048*1024 f32
  u16* xn   = (u16*)(h + (size_t)M_ * D_);  // 2048*1024
  u16* Wq   = xn  + (size_t)M_ * D_;        // 3072*1024
  u16* Wo   = Wq  + (size_t)3 * D_ * D_;    // 1024*1024
  u16* Wf1  = Wo  + (size_t)D_ * D_;        // 4096*1024
  u16* Wf2  = Wf1 + (size_t)4 * D_ * D_;    // 1024*4096
  u16* qkv  = Wf2 + (size_t)4 * D_ * D_;    // 2048*3072
  u16* Vt   = qkv + (size_t)M_ * 3 * D_;    // 2*1024*1024  [bh][hd][t]
  u16* S    = Vt  + (size_t)2 * T_ * D_;    // 16*1024*1024 (fc1 aliases)
  u16* WoutT = Wq;                          // 32000*1024 overlay

  const long sQb = (long)T_ * 3 * D_;       // qkv per-batch row stride
  const long sSb = (long)8 * T_ * T_;
  const long sSh = (long)T_ * T_;
  const float iscale = 0.08838834764831845f;  // 1/sqrt(128)

  embed_kernel<<<M_, 256, 0, stream>>>(x, tok, pos, h);

  for (int l = 0; l < L_; ++l) {
    // weight transpose-converts for this layer (into Wslot)
    convT_kernel<1><<<dim3(48, 16, 1), 256, 0, stream>>>(
        wqkv + (size_t)l * D_ * 3 * D_, Wq, 3 * D_, D_, 0, 0);
    convT_kernel<1><<<dim3(16, 16, 1), 256, 0, stream>>>(
        wo + (size_t)l * D_ * D_, Wo, D_, D_, 0, 0);
    convT_kernel<1><<<dim3(64, 16, 1), 256, 0, stream>>>(
        wfc + (size_t)l * D_ * 4 * D_, Wf1, 4 * D_, D_, 0, 0);
    convT_kernel<1><<<dim3(16, 64, 1), 256, 0, stream>>>(
        wfc2 + (size_t)l * 4 * D_ * D_, Wf2, D_, 4 * D_, 0, 0);

    // ln1 -> xn (bf16)
    ln_bf16<<<M_, 256, 0, stream>>>(h, ln1_g + l * D_, ln1_b + l * D_, xn);
    // qkv = xn @ WqT + bqkv
    gemm2<128, 0, 1, 0, 0><<<dim3(16, 24, 1), 256, 0, stream>>>(
        xn, Wq, bqkv + l * 3 * D_, nullptr, qkv,
        D_, D_, D_, 3 * D_, 1.0f, 0, 0, 0, 0, 0, 0);
    // S = Q @ K^T * iscale (lower-triangle blocks only)
    gemm2<128, 0, 0, 0, 1><<<dim3(8, 8, 16), 256, 0, stream>>>(
        qkv, qkv + D_, nullptr, nullptr, S,
        HD_, 3 * D_, 3 * D_, T_, iscale,
        sQb, (long)HD_, sQb, (long)HD_, sSb, sSh);
    softmax_bf16<<<16 * T_ / 4, 256, 0, stream>>>(S);
    // V^T per batch: qkv cols 2048.. -> Vt[bh][hd][t]
    convT_kernel<0><<<dim3(16, 16, 2), 256, 0, stream>>>(
        qkv + 2 * D_, Vt, 3 * D_, T_, (long)T_ * 3 * D_, (long)T_ * D_);
    // attn = P @ Vt^T (K limited to causal extent)
    gemm2<64, 0, 0, 0, 2><<<dim3(16, 1, 16), 256, 0, stream>>>(
        S, Vt, nullptr, nullptr, xn,
        T_, T_, T_, D_, 1.0f,
        sSb, sSh, (long)T_ * D_, (long)HD_ * T_, (long)T_ * D_, (long)HD_);
    // h += attn @ WoT + bo
    gemm2<64, 0, 1, 2, 0><<<dim3(32, 8, 1), 256, 0, stream>>>(
        xn, Wo, bo + l * D_, h, h,
        D_, D_, D_, D_, 1.0f, 0, 0, 0, 0, 0, 0);
    // ln2 -> xn
    ln_bf16<<<M_, 256, 0, stream>>>(h, ln2_g + l * D_, ln2_b + l * D_, xn);
    // fc1 = gelu(xn @ Wf1T)  (into S region)
    gemm2<128, 1, 0, 0, 0><<<dim3(16, 32, 1), 256, 0, stream>>>(
        xn, Wf1, nullptr, nullptr, S,
        D_, D_, D_, 4 * D_, 1.0f, 0, 0, 0, 0, 0, 0);
    // h += fc1 @ Wf2T
    gemm2<64, 0, 0, 2, 0><<<dim3(32, 8, 1), 256, 0, stream>>>(
        S, Wf2, nullptr, h, h,
        4 * D_, 4 * D_, 4 * D_, D_, 1.0f, 0, 0, 0, 0, 0, 0);
  }

  // final LN -> xn; wout^T into overlay; logits via 8-phase 256^2 kernel
  ln_bf16<<<M_, 256, 0, stream>>>(h, fn_g, fn_b, xn);
  convT_kernel<1><<<dim3(500, 16, 1), 256, 0, stream>>>(
      wout, WoutT, V_, D_, 0, 0);
  gemm8_logits<<<1000, 512, 0, stream>>>(xn, WoutT, bout, out);
}